// Round 3
// baseline (507.753 us; speedup 1.0000x reference)
//
#include <hip/hip_runtime.h>
#include <math.h>

#define B 32
#define S 2048
#define S1 2049
#define D 128
#define H 16
#define DT 2048   // D*H
#define NS 4      // sequence splits per (b,h)
#define ROWS_PER_SPLIT 512
#define EPS 1e-5f
#define SCALE 0.08838834764831845f  // 1/sqrt(128)

typedef float f4v __attribute__((ext_vector_type(4)));

// ---------------------------------------------------------------------------
// Kernel 1: QKV projection + new-token cache append.
// ---------------------------------------------------------------------------
__global__ void __launch_bounds__(256)
qkv_proj_kernel(const float* __restrict__ x,
                const float* __restrict__ Wqkv,
                const float* __restrict__ bqkv,
                float* __restrict__ qkv,
                float* __restrict__ out_k,
                float* __restrict__ out_v) {
    const int b = blockIdx.x;
    const int j = blockIdx.y * 256 + threadIdx.x;
    __shared__ float xs[D];
    if (threadIdx.x < D) xs[threadIdx.x] = x[b * D + threadIdx.x];
    __syncthreads();
    const float* w = Wqkv + (size_t)j * D;
    float acc = bqkv[j];
#pragma unroll
    for (int d = 0; d < D; d += 4) {
        float4 w4 = *reinterpret_cast<const float4*>(w + d);
        acc = fmaf(w4.x, xs[d + 0], acc);
        acc = fmaf(w4.y, xs[d + 1], acc);
        acc = fmaf(w4.z, xs[d + 2], acc);
        acc = fmaf(w4.w, xs[d + 3], acc);
    }
    qkv[(size_t)b * (3 * DT) + j] = acc;

    if (j >= DT) {
        const int r = j - DT;          // 0 .. 2*DT
        const int which = r >> 11;     // 0 = K, 1 = V
        const int hd = r & (DT - 1);   // h*128 + d
        const int h = hd >> 7;
        const int d = hd & 127;
        float* dst = which ? out_v : out_k;
        dst[((size_t)(b * H + h) * S1 + S) * D + d] = acc;
    }
}

// ---------------------------------------------------------------------------
// Kernel 2: fused cache-copy + single-pass online-softmax attention partials.
// Identical structure to round 2 EXCEPT: regular loads/stores (no nontemporal
// hints) — matching the measured 6.3 TB/s copy configuration.
// ---------------------------------------------------------------------------
__global__ void __launch_bounds__(256)
attn_kernel(const float* __restrict__ past_k,
            const float* __restrict__ past_v,
            const float* __restrict__ qkv,
            float* __restrict__ out_k,
            float* __restrict__ out_v,
            float* __restrict__ part_ml,
            float* __restrict__ part_acc) {
    const int bx = blockIdx.x;
    const int split = bx & (NS - 1);
    const int bh = bx >> 2;
    const int b = bh >> 4;
    const int h = bh & (H - 1);
    const int tid  = threadIdx.x;
    const int wave = tid >> 6;
    const int lane = tid & 63;
    const int half = lane >> 5;
    const int l32  = lane & 31;
    const int rg   = wave * 2 + half;   // 0..7

    const f4v* __restrict__ kin  = (const f4v*)past_k + (size_t)(b * H + h) * S * 32;
    const f4v* __restrict__ vin  = (const f4v*)past_v + (size_t)(b * H + h) * S * 32;
    f4v* __restrict__ kout = (f4v*)out_k + (size_t)(b * H + h) * S1 * 32;
    f4v* __restrict__ vout = (f4v*)out_v + (size_t)(b * H + h) * S1 * 32;

    const f4v q4 = ((const f4v*)qkv)[(size_t)b * (3 * DT / 4) + h * 32 + l32];

    const int s0 = split * ROWS_PER_SPLIT + rg;

    float m = -1e30f;
    float l = 0.f;
    f4v acc = (f4v){0.f, 0.f, 0.f, 0.f};

#pragma unroll 4
    for (int it = 0; it < ROWS_PER_SPLIT / 8; ++it) {
        const int s = s0 + it * 8;
        const size_t off = (size_t)s * 32 + l32;
        f4v k4 = kin[off];
        kout[off] = k4;
        f4v t = k4 * q4;
        float p = t.x + t.y + t.z + t.w;
        p += __shfl_xor(p, 1);
        p += __shfl_xor(p, 2);
        p += __shfl_xor(p, 4);
        p += __shfl_xor(p, 8);
        p += __shfl_xor(p, 16);
        p *= SCALE;
        f4v v4 = vin[off];
        vout[off] = v4;
        const float mn = fmaxf(m, p);
        const float c = __expf(m - mn);
        const float e = __expf(p - mn);
        l = l * c + e;
        acc = acc * c;
        acc += v4 * e;
        m = mn;
    }

    // ---- block combine over 8 rowgroups ----
    __shared__ float sm[8];
    __shared__ float sl[8];
    __shared__ float sacc[8 * D];
    ((f4v*)sacc)[rg * 32 + l32] = acc;
    if (l32 == 0) { sm[rg] = m; sl[rg] = l; }
    __syncthreads();

    if (tid < D) {
        float M = sm[0];
#pragma unroll
        for (int g = 1; g < 8; ++g) M = fmaxf(M, sm[g]);
        float L = 0.f, y = 0.f;
#pragma unroll
        for (int g = 0; g < 8; ++g) {
            const float wgt = __expf(sm[g] - M);
            L += wgt * sl[g];
            y = fmaf(wgt, sacc[g * D + tid], y);
        }
        part_acc[(size_t)bx * D + tid] = y;
        if (tid == 0) {
            part_ml[2 * bx + 0] = M;
            part_ml[2 * bx + 1] = L;
        }
    }
}

// ---------------------------------------------------------------------------
// Kernel 3: combine partials (+ new-token) -> y_heads, out-proj + residual
// + LayerNorm.  One block per b, 1024 threads.
// ---------------------------------------------------------------------------
__global__ void __launch_bounds__(1024)
out_proj_kernel(const float* __restrict__ x,
                const float* __restrict__ qkv,
                const float* __restrict__ part_ml,
                const float* __restrict__ part_acc,
                const float* __restrict__ Wout,
                const float* __restrict__ bout,
                float* __restrict__ out) {
    const int b = blockIdx.x;
    const int t = threadIdx.x;
    __shared__ float ys[DT];        // combined attention output, 8 KB
    __shared__ float pp[D * 8];     // GEMV partials, 4 KB
    __shared__ float tb[D];

    // ---- combine phase: wave w = head h ----
    {
        const int h = t >> 6;
        const int lane = t & 63;
        const float* qp   = qkv + (size_t)b * (3 * DT) + h * D;
        const float* knew = qp + DT;
        const float* vnew = qp + 2 * DT;
        float pd = qp[2 * lane] * knew[2 * lane] + qp[2 * lane + 1] * knew[2 * lane + 1];
        pd += __shfl_xor(pd, 1);
        pd += __shfl_xor(pd, 2);
        pd += __shfl_xor(pd, 4);
        pd += __shfl_xor(pd, 8);
        pd += __shfl_xor(pd, 16);
        pd += __shfl_xor(pd, 32);
        const float s = pd * SCALE;

        const int bh = b * H + h;
        float m0 = part_ml[2 * (bh * NS + 0)], l0 = part_ml[2 * (bh * NS + 0) + 1];
        float m1 = part_ml[2 * (bh * NS + 1)], l1 = part_ml[2 * (bh * NS + 1) + 1];
        float m2 = part_ml[2 * (bh * NS + 2)], l2 = part_ml[2 * (bh * NS + 2) + 1];
        float m3 = part_ml[2 * (bh * NS + 3)], l3 = part_ml[2 * (bh * NS + 3) + 1];
        float M = fmaxf(fmaxf(fmaxf(m0, m1), fmaxf(m2, m3)), s);
        const float w0 = __expf(m0 - M), w1 = __expf(m1 - M);
        const float w2 = __expf(m2 - M), w3 = __expf(m3 - M);
        const float wn = __expf(s - M);
        const float L = w0 * l0 + w1 * l1 + w2 * l2 + w3 * l3 + wn;
        const float invL = 1.0f / L;
#pragma unroll
        for (int r = 0; r < 2; ++r) {
            const int d = lane + r * 64;
            float y = wn * vnew[d];
            y = fmaf(w0, part_acc[(size_t)(bh * NS + 0) * D + d], y);
            y = fmaf(w1, part_acc[(size_t)(bh * NS + 1) * D + d], y);
            y = fmaf(w2, part_acc[(size_t)(bh * NS + 2) * D + d], y);
            y = fmaf(w3, part_acc[(size_t)(bh * NS + 3) * D + d], y);
            ys[h * D + d] = y * invL;
        }
    }
    __syncthreads();

    // ---- GEMV: out[d] = Wout[d,:] . ys + bout[d] ----
    {
        const int d = t >> 3;
        const int sub = t & 7;
        const float* w = Wout + (size_t)d * DT + sub * 256;
        const float* y = ys + sub * 256;
        float acc = 0.f;
#pragma unroll
        for (int j = 0; j < 256; j += 4) {
            float4 w4 = *reinterpret_cast<const float4*>(w + j);
            acc = fmaf(w4.x, y[j + 0], acc);
            acc = fmaf(w4.y, y[j + 1], acc);
            acc = fmaf(w4.z, y[j + 2], acc);
            acc = fmaf(w4.w, y[j + 3], acc);
        }
        pp[d * 8 + sub] = acc;
    }
    __syncthreads();

    // ---- reduce + bias + residual + LayerNorm (threads 0..127 active) ----
    float val = 0.f;
    if (t < D) {
        float a = 0.f;
#pragma unroll
        for (int g = 0; g < 8; ++g) a += pp[t * 8 + g];
        val = a + bout[t] + x[b * D + t];
        tb[t] = val;
    }
    __syncthreads();
    for (int off = 64; off > 0; off >>= 1) {
        if (t < off) tb[t] += tb[t + off];
        __syncthreads();
    }
    const float mu = tb[0] * (1.0f / D);
    __syncthreads();
    const float diff = val - mu;
    if (t < D) tb[t] = diff * diff;
    __syncthreads();
    for (int off = 64; off > 0; off >>= 1) {
        if (t < off) tb[t] += tb[t + off];
        __syncthreads();
    }
    const float var = tb[0] * (1.0f / D);
    if (t < D) out[(size_t)b * D + t] = diff / sqrtf(var + EPS);
}

// ---------------------------------------------------------------------------
extern "C" void kernel_launch(void* const* d_in, const int* in_sizes, int n_in,
                              void* d_out, int out_size, void* d_ws, size_t ws_size,
                              hipStream_t stream) {
    const float* x      = (const float*)d_in[0];
    const float* past_k = (const float*)d_in[1];
    const float* past_v = (const float*)d_in[2];
    const float* Wqkv   = (const float*)d_in[3];
    const float* bqkv   = (const float*)d_in[4];
    const float* Wout   = (const float*)d_in[5];
    const float* bout   = (const float*)d_in[6];

    float* out   = (float*)d_out;                       // (B,1,D)
    float* out_k = out + (size_t)B * D;                 // (B,H,S1,D)
    float* out_v = out_k + (size_t)B * H * S1 * D;      // (B,H,S1,D)

    float* qkv      = (float*)d_ws;                     // B*3*DT
    float* part_ml  = qkv + (size_t)B * 3 * DT;         // 2*B*H*NS
    float* part_acc = part_ml + 2 * B * H * NS;         // B*H*NS*D

    qkv_proj_kernel<<<dim3(B, (3 * DT) / 256), 256, 0, stream>>>(
        x, Wqkv, bqkv, qkv, out_k, out_v);
    attn_kernel<<<B * H * NS, 256, 0, stream>>>(
        past_k, past_v, qkv, out_k, out_v, part_ml, part_acc);
    out_proj_kernel<<<B, 1024, 0, stream>>>(
        x, qkv, part_ml, part_acc, Wout, bout, out);
}

// Round 4
// 468.781 us; speedup vs baseline: 1.0831x; 1.0831x over previous
//
#include <hip/hip_runtime.h>
#include <math.h>

#define B 32
#define S 2048
#define S1 2049
#define D 128
#define H 16
#define DT 2048   // D*H
#define NS 4      // sequence splits per (b,h)
#define RPS 512   // rows per split
#define EPS 1e-5f
#define SCALE 0.08838834764831845f  // 1/sqrt(128)

typedef float f4v __attribute__((ext_vector_type(4)));

// ---------------------------------------------------------------------------
// Kernel 1: QKV projection + new-token cache append.
// ---------------------------------------------------------------------------
__global__ void __launch_bounds__(256)
qkv_proj_kernel(const float* __restrict__ x,
                const float* __restrict__ Wqkv,
                const float* __restrict__ bqkv,
                float* __restrict__ qkv,
                float* __restrict__ out_k,
                float* __restrict__ out_v) {
    const int b = blockIdx.x;
    const int j = blockIdx.y * 256 + threadIdx.x;
    __shared__ float xs[D];
    if (threadIdx.x < D) xs[threadIdx.x] = x[b * D + threadIdx.x];
    __syncthreads();
    const float* w = Wqkv + (size_t)j * D;
    float acc = bqkv[j];
#pragma unroll
    for (int d = 0; d < D; d += 4) {
        float4 w4 = *reinterpret_cast<const float4*>(w + d);
        acc = fmaf(w4.x, xs[d + 0], acc);
        acc = fmaf(w4.y, xs[d + 1], acc);
        acc = fmaf(w4.z, xs[d + 2], acc);
        acc = fmaf(w4.w, xs[d + 3], acc);
    }
    qkv[(size_t)b * (3 * DT) + j] = acc;

    if (j >= DT) {
        const int r = j - DT;          // 0 .. 2*DT
        const int which = r >> 11;     // 0 = K, 1 = V
        const int hd = r & (DT - 1);   // h*128 + d
        const int h = hd >> 7;
        const int d = hd & 127;
        float* dst = which ? out_v : out_k;
        dst[((size_t)(b * H + h) * S1 + S) * D + d] = acc;
    }
}

// ---------------------------------------------------------------------------
// Kernel 2: fused cache-copy + attention partials, PHASE-SPLIT.
// Grid: B*H*NS blocks, 256 threads = 8 half-waves; half-wave rg owns rows
// r = rg + 8k of its 512-row split (lane l32 owns 16B column l32).
// K-pass:  load K -> store cache -> dot -> score to LDS   (no carried deps)
// softmax: block max + exp + sum over the 512 LDS scores
// V-pass:  load V -> store cache -> acc += sc[r] * v      (1 carried FMA)
// Output:  unnormalized partial acc[128] + (M, L) per split.
// ---------------------------------------------------------------------------
__global__ void __launch_bounds__(256)
attn_kernel(const float* __restrict__ past_k,
            const float* __restrict__ past_v,
            const float* __restrict__ qkv,
            float* __restrict__ out_k,
            float* __restrict__ out_v,
            float* __restrict__ part_ml,
            float* __restrict__ part_acc) {
    const int bx = blockIdx.x;
    const int split = bx & (NS - 1);
    const int bh = bx >> 2;
    const int b = bh >> 4;
    const int h = bh & (H - 1);
    const int tid  = threadIdx.x;
    const int wave = tid >> 6;
    const int lane = tid & 63;
    const int half = lane >> 5;
    const int l32  = lane & 31;
    const int rg   = wave * 2 + half;   // 0..7

    __shared__ float sc[RPS];       // scores -> exp(score - M)
    __shared__ float swm[4];
    __shared__ float swl[4];
    __shared__ float sacc[8 * D];

    const f4v* __restrict__ kin  = (const f4v*)past_k + (size_t)(b * H + h) * S * 32;
    const f4v* __restrict__ vin  = (const f4v*)past_v + (size_t)(b * H + h) * S * 32;
    f4v* __restrict__ kout = (f4v*)out_k + (size_t)(b * H + h) * S1 * 32;
    f4v* __restrict__ vout = (f4v*)out_v + (size_t)(b * H + h) * S1 * 32;

    const f4v q4 = ((const f4v*)qkv)[(size_t)b * (3 * DT / 4) + h * 32 + l32];

    const size_t base = (size_t)split * RPS * 32;

    // ---- K-pass: copy + scores (no loop-carried dependencies) ----
#pragma unroll 8
    for (int it = 0; it < RPS / 8; ++it) {
        const int r = it * 8 + rg;
        const size_t off = base + (size_t)r * 32 + l32;
        f4v k4 = __builtin_nontemporal_load(&kin[off]);
        __builtin_nontemporal_store(k4, &kout[off]);
        f4v t = k4 * q4;
        float p = t.x + t.y + t.z + t.w;
        p += __shfl_xor(p, 1);
        p += __shfl_xor(p, 2);
        p += __shfl_xor(p, 4);
        p += __shfl_xor(p, 8);
        p += __shfl_xor(p, 16);
        if (l32 == 0) sc[r] = p * SCALE;
    }
    __syncthreads();

    // ---- block softmax over sc[0..512) ----
    float s0v = sc[tid];
    float s1v = sc[tid + 256];
    float m = fmaxf(s0v, s1v);
#pragma unroll
    for (int off = 1; off < 64; off <<= 1) m = fmaxf(m, __shfl_xor(m, off));
    if (lane == 0) swm[wave] = m;
    __syncthreads();
    const float M = fmaxf(fmaxf(swm[0], swm[1]), fmaxf(swm[2], swm[3]));
    const float e0 = __expf(s0v - M);
    const float e1 = __expf(s1v - M);
    sc[tid] = e0;
    sc[tid + 256] = e1;
    float lsum = e0 + e1;
#pragma unroll
    for (int off = 1; off < 64; off <<= 1) lsum += __shfl_xor(lsum, off);
    if (lane == 0) swl[wave] = lsum;
    __syncthreads();
    const float L = swl[0] + swl[1] + swl[2] + swl[3];

    // ---- V-pass: copy + weighted accumulate ----
    f4v acc = (f4v){0.f, 0.f, 0.f, 0.f};
#pragma unroll 8
    for (int it = 0; it < RPS / 8; ++it) {
        const int r = it * 8 + rg;
        const size_t off = base + (size_t)r * 32 + l32;
        f4v v4 = __builtin_nontemporal_load(&vin[off]);
        __builtin_nontemporal_store(v4, &vout[off]);
        const float p = sc[r];
        acc += v4 * p;
    }

    // ---- combine 8 rowgroups ----
    ((f4v*)sacc)[rg * 32 + l32] = acc;
    __syncthreads();

    if (tid < D) {
        float y = 0.f;
#pragma unroll
        for (int g = 0; g < 8; ++g) y += sacc[g * D + tid];
        part_acc[(size_t)bx * D + tid] = y;
        if (tid == 0) {
            part_ml[2 * bx + 0] = M;
            part_ml[2 * bx + 1] = L;
        }
    }
}

// ---------------------------------------------------------------------------
// Kernel 3: combine partials (+ new-token) -> y_heads, out-proj + residual
// + LayerNorm.  One block per b, 1024 threads.
// ---------------------------------------------------------------------------
__global__ void __launch_bounds__(1024)
out_proj_kernel(const float* __restrict__ x,
                const float* __restrict__ qkv,
                const float* __restrict__ part_ml,
                const float* __restrict__ part_acc,
                const float* __restrict__ Wout,
                const float* __restrict__ bout,
                float* __restrict__ out) {
    const int b = blockIdx.x;
    const int t = threadIdx.x;
    __shared__ float ys[DT];        // combined attention output, 8 KB
    __shared__ float pp[D * 8];     // GEMV partials, 4 KB
    __shared__ float tb[D];

    // ---- combine phase: wave w = head h ----
    {
        const int h = t >> 6;
        const int lane = t & 63;
        const float* qp   = qkv + (size_t)b * (3 * DT) + h * D;
        const float* knew = qp + DT;
        const float* vnew = qp + 2 * DT;
        float pd = qp[2 * lane] * knew[2 * lane] + qp[2 * lane + 1] * knew[2 * lane + 1];
        pd += __shfl_xor(pd, 1);
        pd += __shfl_xor(pd, 2);
        pd += __shfl_xor(pd, 4);
        pd += __shfl_xor(pd, 8);
        pd += __shfl_xor(pd, 16);
        pd += __shfl_xor(pd, 32);
        const float s = pd * SCALE;

        const int bh = b * H + h;
        float m0 = part_ml[2 * (bh * NS + 0)], l0 = part_ml[2 * (bh * NS + 0) + 1];
        float m1 = part_ml[2 * (bh * NS + 1)], l1 = part_ml[2 * (bh * NS + 1) + 1];
        float m2 = part_ml[2 * (bh * NS + 2)], l2 = part_ml[2 * (bh * NS + 2) + 1];
        float m3 = part_ml[2 * (bh * NS + 3)], l3 = part_ml[2 * (bh * NS + 3) + 1];
        float M = fmaxf(fmaxf(fmaxf(m0, m1), fmaxf(m2, m3)), s);
        const float w0 = __expf(m0 - M), w1 = __expf(m1 - M);
        const float w2 = __expf(m2 - M), w3 = __expf(m3 - M);
        const float wn = __expf(s - M);
        const float L = w0 * l0 + w1 * l1 + w2 * l2 + w3 * l3 + wn;
        const float invL = 1.0f / L;
#pragma unroll
        for (int r = 0; r < 2; ++r) {
            const int d = lane + r * 64;
            float y = wn * vnew[d];
            y = fmaf(w0, part_acc[(size_t)(bh * NS + 0) * D + d], y);
            y = fmaf(w1, part_acc[(size_t)(bh * NS + 1) * D + d], y);
            y = fmaf(w2, part_acc[(size_t)(bh * NS + 2) * D + d], y);
            y = fmaf(w3, part_acc[(size_t)(bh * NS + 3) * D + d], y);
            ys[h * D + d] = y * invL;
        }
    }
    __syncthreads();

    // ---- GEMV: out[d] = Wout[d,:] . ys + bout[d] ----
    {
        const int d = t >> 3;
        const int sub = t & 7;
        const float* w = Wout + (size_t)d * DT + sub * 256;
        const float* y = ys + sub * 256;
        float acc = 0.f;
#pragma unroll
        for (int j = 0; j < 256; j += 4) {
            float4 w4 = *reinterpret_cast<const float4*>(w + j);
            acc = fmaf(w4.x, y[j + 0], acc);
            acc = fmaf(w4.y, y[j + 1], acc);
            acc = fmaf(w4.z, y[j + 2], acc);
            acc = fmaf(w4.w, y[j + 3], acc);
        }
        pp[d * 8 + sub] = acc;
    }
    __syncthreads();

    // ---- reduce + bias + residual + LayerNorm (threads 0..127 active) ----
    float val = 0.f;
    if (t < D) {
        float a = 0.f;
#pragma unroll
        for (int g = 0; g < 8; ++g) a += pp[t * 8 + g];
        val = a + bout[t] + x[b * D + t];
        tb[t] = val;
    }
    __syncthreads();
    for (int off = 64; off > 0; off >>= 1) {
        if (t < off) tb[t] += tb[t + off];
        __syncthreads();
    }
    const float mu = tb[0] * (1.0f / D);
    __syncthreads();
    const float diff = val - mu;
    if (t < D) tb[t] = diff * diff;
    __syncthreads();
    for (int off = 64; off > 0; off >>= 1) {
        if (t < off) tb[t] += tb[t + off];
        __syncthreads();
    }
    const float var = tb[0] * (1.0f / D);
    if (t < D) out[(size_t)b * D + t] = diff / sqrtf(var + EPS);
}

// ---------------------------------------------------------------------------
extern "C" void kernel_launch(void* const* d_in, const int* in_sizes, int n_in,
                              void* d_out, int out_size, void* d_ws, size_t ws_size,
                              hipStream_t stream) {
    const float* x      = (const float*)d_in[0];
    const float* past_k = (const float*)d_in[1];
    const float* past_v = (const float*)d_in[2];
    const float* Wqkv   = (const float*)d_in[3];
    const float* bqkv   = (const float*)d_in[4];
    const float* Wout   = (const float*)d_in[5];
    const float* bout   = (const float*)d_in[6];

    float* out   = (float*)d_out;                       // (B,1,D)
    float* out_k = out + (size_t)B * D;                 // (B,H,S1,D)
    float* out_v = out_k + (size_t)B * H * S1 * D;      // (B,H,S1,D)

    float* qkv      = (float*)d_ws;                     // B*3*DT
    float* part_ml  = qkv + (size_t)B * 3 * DT;         // 2*B*H*NS
    float* part_acc = part_ml + 2 * B * H * NS;         // B*H*NS*D

    qkv_proj_kernel<<<dim3(B, (3 * DT) / 256), 256, 0, stream>>>(
        x, Wqkv, bqkv, qkv, out_k, out_v);
    attn_kernel<<<B * H * NS, 256, 0, stream>>>(
        past_k, past_v, qkv, out_k, out_v, part_ml, part_acc);
    out_proj_kernel<<<B, 1024, 0, stream>>>(
        x, qkv, part_ml, part_acc, Wout, bout, out);
}

// Round 5
// 448.783 us; speedup vs baseline: 1.1314x; 1.0446x over previous
//
#include <hip/hip_runtime.h>
#include <math.h>

#define B 32
#define S 2048
#define S1 2049
#define D 128
#define H 16
#define DT 2048   // D*H
#define NS 2      // sequence splits per (b,h)
#define RPS 1024  // rows per split
#define EPS 1e-5f
#define SCALE 0.08838834764831845f  // 1/sqrt(128)

typedef float f4v __attribute__((ext_vector_type(4)));

// ---------------------------------------------------------------------------
// Kernel 1: QKV projection + new-token cache append.
// ---------------------------------------------------------------------------
__global__ void __launch_bounds__(256)
qkv_proj_kernel(const float* __restrict__ x,
                const float* __restrict__ Wqkv,
                const float* __restrict__ bqkv,
                float* __restrict__ qkv,
                float* __restrict__ out_k,
                float* __restrict__ out_v) {
    const int b = blockIdx.x;
    const int j = blockIdx.y * 256 + threadIdx.x;
    __shared__ float xs[D];
    if (threadIdx.x < D) xs[threadIdx.x] = x[b * D + threadIdx.x];
    __syncthreads();
    const float* w = Wqkv + (size_t)j * D;
    float acc = bqkv[j];
#pragma unroll
    for (int d = 0; d < D; d += 4) {
        float4 w4 = *reinterpret_cast<const float4*>(w + d);
        acc = fmaf(w4.x, xs[d + 0], acc);
        acc = fmaf(w4.y, xs[d + 1], acc);
        acc = fmaf(w4.z, xs[d + 2], acc);
        acc = fmaf(w4.w, xs[d + 3], acc);
    }
    qkv[(size_t)b * (3 * DT) + j] = acc;

    if (j >= DT) {
        const int r = j - DT;          // 0 .. 2*DT
        const int which = r >> 11;     // 0 = K, 1 = V
        const int hd = r & (DT - 1);   // h*128 + d
        const int h = hd >> 7;
        const int d = hd & 127;
        float* dst = which ? out_v : out_k;
        dst[((size_t)(b * H + h) * S1 + S) * D + d] = acc;
    }
}

// ---------------------------------------------------------------------------
// Kernel 2: fused cache-copy + attention partials, phase-split.
// Grid: B*H*NS blocks of 512 threads = 16 half-waves; half-wave rg owns rows
// r = rg + 16k of its 1024-row split (lane l32 owns 16B column l32).
// Per micro-step the block touches a CONTIGUOUS 8 KB window (16 rows), and
// there are only 1024 read + 1024 write streams device-wide (vs 2048+2048
// in the previous round) -> better DRAM row-buffer locality.
// ---------------------------------------------------------------------------
__global__ void __launch_bounds__(512)
attn_kernel(const float* __restrict__ past_k,
            const float* __restrict__ past_v,
            const float* __restrict__ qkv,
            float* __restrict__ out_k,
            float* __restrict__ out_v,
            float* __restrict__ part_ml,
            float* __restrict__ part_acc) {
    const int bx = blockIdx.x;
    const int split = bx & (NS - 1);
    const int bh = bx >> 1;          // NS = 2
    const int b = bh >> 4;
    const int h = bh & (H - 1);
    const int tid  = threadIdx.x;
    const int wave = tid >> 6;       // 0..7
    const int lane = tid & 63;
    const int half = lane >> 5;
    const int l32  = lane & 31;
    const int rg   = wave * 2 + half;   // 0..15

    __shared__ float sc[RPS];        // 4 KB: scores -> exp(score - M)
    __shared__ float swm[8];
    __shared__ float swl[8];
    __shared__ float sacc[16 * D];   // 8 KB

    const f4v* __restrict__ kin  = (const f4v*)past_k + (size_t)(b * H + h) * S * 32;
    const f4v* __restrict__ vin  = (const f4v*)past_v + (size_t)(b * H + h) * S * 32;
    f4v* __restrict__ kout = (f4v*)out_k + (size_t)(b * H + h) * S1 * 32;
    f4v* __restrict__ vout = (f4v*)out_v + (size_t)(b * H + h) * S1 * 32;

    const f4v q4 = ((const f4v*)qkv)[(size_t)b * (3 * DT / 4) + h * 32 + l32];

    const size_t base = (size_t)split * RPS * 32;

    // ---- K-pass: copy + scores (no loop-carried dependencies) ----
#pragma unroll 8
    for (int it = 0; it < RPS / 16; ++it) {
        const int r = it * 16 + rg;
        const size_t off = base + (size_t)r * 32 + l32;
        f4v k4 = __builtin_nontemporal_load(&kin[off]);
        __builtin_nontemporal_store(k4, &kout[off]);
        f4v t = k4 * q4;
        float p = t.x + t.y + t.z + t.w;
        p += __shfl_xor(p, 1);
        p += __shfl_xor(p, 2);
        p += __shfl_xor(p, 4);
        p += __shfl_xor(p, 8);
        p += __shfl_xor(p, 16);
        if (l32 == 0) sc[r] = p * SCALE;
    }
    __syncthreads();

    // ---- block softmax over sc[0..1024) ----
    float s0v = sc[tid];
    float s1v = sc[tid + 512];
    float m = fmaxf(s0v, s1v);
#pragma unroll
    for (int off = 1; off < 64; off <<= 1) m = fmaxf(m, __shfl_xor(m, off));
    if (lane == 0) swm[wave] = m;
    __syncthreads();
    float M = swm[0];
#pragma unroll
    for (int g = 1; g < 8; ++g) M = fmaxf(M, swm[g]);
    const float e0 = __expf(s0v - M);
    const float e1 = __expf(s1v - M);
    sc[tid] = e0;
    sc[tid + 512] = e1;
    float lsum = e0 + e1;
#pragma unroll
    for (int off = 1; off < 64; off <<= 1) lsum += __shfl_xor(lsum, off);
    if (lane == 0) swl[wave] = lsum;
    __syncthreads();
    float L = swl[0];
#pragma unroll
    for (int g = 1; g < 8; ++g) L += swl[g];

    // ---- V-pass: copy + weighted accumulate (1 carried FMA) ----
    f4v acc = (f4v){0.f, 0.f, 0.f, 0.f};
#pragma unroll 8
    for (int it = 0; it < RPS / 16; ++it) {
        const int r = it * 16 + rg;
        const size_t off = base + (size_t)r * 32 + l32;
        f4v v4 = __builtin_nontemporal_load(&vin[off]);
        __builtin_nontemporal_store(v4, &vout[off]);
        const float p = sc[r];
        acc += v4 * p;
    }

    // ---- combine 16 rowgroups ----
    ((f4v*)sacc)[rg * 32 + l32] = acc;
    __syncthreads();

    if (tid < D) {
        float y = 0.f;
#pragma unroll
        for (int g = 0; g < 16; ++g) y += sacc[g * D + tid];
        part_acc[(size_t)bx * D + tid] = y;
        if (tid == 0) {
            part_ml[2 * bx + 0] = M;
            part_ml[2 * bx + 1] = L;
        }
    }
}

// ---------------------------------------------------------------------------
// Kernel 3: combine partials (+ new-token) -> y_heads, out-proj + residual
// + LayerNorm.  One block per b, 1024 threads.
// ---------------------------------------------------------------------------
__global__ void __launch_bounds__(1024)
out_proj_kernel(const float* __restrict__ x,
                const float* __restrict__ qkv,
                const float* __restrict__ part_ml,
                const float* __restrict__ part_acc,
                const float* __restrict__ Wout,
                const float* __restrict__ bout,
                float* __restrict__ out) {
    const int b = blockIdx.x;
    const int t = threadIdx.x;
    __shared__ float ys[DT];        // combined attention output, 8 KB
    __shared__ float pp[D * 8];     // GEMV partials, 4 KB
    __shared__ float tb[D];

    // ---- combine phase: wave w = head h ----
    {
        const int h = t >> 6;
        const int lane = t & 63;
        const float* qp   = qkv + (size_t)b * (3 * DT) + h * D;
        const float* knew = qp + DT;
        const float* vnew = qp + 2 * DT;
        float pd = qp[2 * lane] * knew[2 * lane] + qp[2 * lane + 1] * knew[2 * lane + 1];
        pd += __shfl_xor(pd, 1);
        pd += __shfl_xor(pd, 2);
        pd += __shfl_xor(pd, 4);
        pd += __shfl_xor(pd, 8);
        pd += __shfl_xor(pd, 16);
        pd += __shfl_xor(pd, 32);
        const float s = pd * SCALE;

        const int bh = b * H + h;
        float pm[NS], pl[NS];
#pragma unroll
        for (int g = 0; g < NS; ++g) {
            pm[g] = part_ml[2 * (bh * NS + g) + 0];
            pl[g] = part_ml[2 * (bh * NS + g) + 1];
        }
        float M = s;
#pragma unroll
        for (int g = 0; g < NS; ++g) M = fmaxf(M, pm[g]);
        float wg[NS];
        float L = __expf(s - M);
        const float wn = L;
#pragma unroll
        for (int g = 0; g < NS; ++g) {
            wg[g] = __expf(pm[g] - M);
            L += wg[g] * pl[g];
        }
        const float invL = 1.0f / L;
#pragma unroll
        for (int r = 0; r < 2; ++r) {
            const int d = lane + r * 64;
            float y = wn * vnew[d];
#pragma unroll
            for (int g = 0; g < NS; ++g)
                y = fmaf(wg[g], part_acc[(size_t)(bh * NS + g) * D + d], y);
            ys[h * D + d] = y * invL;
        }
    }
    __syncthreads();

    // ---- GEMV: out[d] = Wout[d,:] . ys + bout[d] ----
    {
        const int d = t >> 3;
        const int sub = t & 7;
        const float* w = Wout + (size_t)d * DT + sub * 256;
        const float* y = ys + sub * 256;
        float acc = 0.f;
#pragma unroll
        for (int j = 0; j < 256; j += 4) {
            float4 w4 = *reinterpret_cast<const float4*>(w + j);
            acc = fmaf(w4.x, y[j + 0], acc);
            acc = fmaf(w4.y, y[j + 1], acc);
            acc = fmaf(w4.z, y[j + 2], acc);
            acc = fmaf(w4.w, y[j + 3], acc);
        }
        pp[d * 8 + sub] = acc;
    }
    __syncthreads();

    // ---- reduce + bias + residual + LayerNorm (threads 0..127 active) ----
    float val = 0.f;
    if (t < D) {
        float a = 0.f;
#pragma unroll
        for (int g = 0; g < 8; ++g) a += pp[t * 8 + g];
        val = a + bout[t] + x[b * D + t];
        tb[t] = val;
    }
    __syncthreads();
    for (int off = 64; off > 0; off >>= 1) {
        if (t < off) tb[t] += tb[t + off];
        __syncthreads();
    }
    const float mu = tb[0] * (1.0f / D);
    __syncthreads();
    const float diff = val - mu;
    if (t < D) tb[t] = diff * diff;
    __syncthreads();
    for (int off = 64; off > 0; off >>= 1) {
        if (t < off) tb[t] += tb[t + off];
        __syncthreads();
    }
    const float var = tb[0] * (1.0f / D);
    if (t < D) out[(size_t)b * D + t] = diff / sqrtf(var + EPS);
}

// ---------------------------------------------------------------------------
extern "C" void kernel_launch(void* const* d_in, const int* in_sizes, int n_in,
                              void* d_out, int out_size, void* d_ws, size_t ws_size,
                              hipStream_t stream) {
    const float* x      = (const float*)d_in[0];
    const float* past_k = (const float*)d_in[1];
    const float* past_v = (const float*)d_in[2];
    const float* Wqkv   = (const float*)d_in[3];
    const float* bqkv   = (const float*)d_in[4];
    const float* Wout   = (const float*)d_in[5];
    const float* bout   = (const float*)d_in[6];

    float* out   = (float*)d_out;                       // (B,1,D)
    float* out_k = out + (size_t)B * D;                 // (B,H,S1,D)
    float* out_v = out_k + (size_t)B * H * S1 * D;      // (B,H,S1,D)

    float* qkv      = (float*)d_ws;                     // B*3*DT
    float* part_ml  = qkv + (size_t)B * 3 * DT;         // 2*B*H*NS
    float* part_acc = part_ml + 2 * B * H * NS;         // B*H*NS*D

    qkv_proj_kernel<<<dim3(B, (3 * DT) / 256), 256, 0, stream>>>(
        x, Wqkv, bqkv, qkv, out_k, out_v);
    attn_kernel<<<B * H * NS, 512, 0, stream>>>(
        past_k, past_v, qkv, out_k, out_v, part_ml, part_acc);
    out_proj_kernel<<<B, 1024, 0, stream>>>(
        x, qkv, part_ml, part_acc, Wout, bout, out);
}

// Round 6
// 445.279 us; speedup vs baseline: 1.1403x; 1.0079x over previous
//
#include <hip/hip_runtime.h>
#include <math.h>

#define B 32
#define S 2048
#define S1 2049
#define D 128
#define H 16
#define DT 2048   // D*H
#define EPS 1e-5f
#define SCALE 0.08838834764831845f  // 1/sqrt(128)

typedef float f4v __attribute__((ext_vector_type(4)));

// ---------------------------------------------------------------------------
// Kernel 1: QKV projection + new-token cache append.
// ---------------------------------------------------------------------------
__global__ void __launch_bounds__(256)
qkv_proj_kernel(const float* __restrict__ x,
                const float* __restrict__ Wqkv,
                const float* __restrict__ bqkv,
                float* __restrict__ qkv,
                float* __restrict__ out_k,
                float* __restrict__ out_v) {
    const int b = blockIdx.x;
    const int j = blockIdx.y * 256 + threadIdx.x;
    __shared__ float xs[D];
    if (threadIdx.x < D) xs[threadIdx.x] = x[b * D + threadIdx.x];
    __syncthreads();
    const float* w = Wqkv + (size_t)j * D;
    float acc = bqkv[j];
#pragma unroll
    for (int d = 0; d < D; d += 4) {
        float4 w4 = *reinterpret_cast<const float4*>(w + d);
        acc = fmaf(w4.x, xs[d + 0], acc);
        acc = fmaf(w4.y, xs[d + 1], acc);
        acc = fmaf(w4.z, xs[d + 2], acc);
        acc = fmaf(w4.w, xs[d + 3], acc);
    }
    qkv[(size_t)b * (3 * DT) + j] = acc;

    if (j >= DT) {
        const int r = j - DT;          // 0 .. 2*DT
        const int which = r >> 11;     // 0 = K, 1 = V
        const int hd = r & (DT - 1);   // h*128 + d
        const int h = hd >> 7;
        const int d = hd & 127;
        float* dst = which ? out_v : out_k;
        dst[((size_t)(b * H + h) * S1 + S) * D + d] = acc;
    }
}

// ---------------------------------------------------------------------------
// Kernel 2: fused cache-copy + FULL single-(b,h) attention, phase-split.
// Grid: B*H = 512 blocks of 1024 threads = 32 half-waves; half-wave rg owns
// rows r = rg + 32k (k=0..63); lane l32 owns 16B column l32.
// Streams per phase: 512 read + 512 write device-wide; per-step block
// footprint 16 KB contiguous.
// New token handled in-block: score into sc[2048], value folded at the end.
// Output: normalized attention result ys[bh*D + d]  (no partials).
// ---------------------------------------------------------------------------
__global__ void __launch_bounds__(1024)
attn_kernel(const float* __restrict__ past_k,
            const float* __restrict__ past_v,
            const float* __restrict__ qkv,
            float* __restrict__ out_k,
            float* __restrict__ out_v,
            float* __restrict__ ys_g) {
    const int bh = blockIdx.x;
    const int b = bh >> 4;
    const int h = bh & (H - 1);
    const int tid  = threadIdx.x;
    const int wave = tid >> 6;       // 0..15
    const int lane = tid & 63;
    const int l32  = tid & 31;
    const int rg   = tid >> 5;       // half-wave 0..31

    __shared__ float sc[S1 + 3];     // 2049 scores (pad to keep alignment)
    __shared__ float swm[16];
    __shared__ float swl[16];
    __shared__ float sacc[32 * D];   // 16 KB

    const f4v* __restrict__ kin  = (const f4v*)past_k + (size_t)bh * S * 32;
    const f4v* __restrict__ vin  = (const f4v*)past_v + (size_t)bh * S * 32;
    f4v* __restrict__ kout = (f4v*)out_k + (size_t)bh * S1 * 32;
    f4v* __restrict__ vout = (f4v*)out_v + (size_t)bh * S1 * 32;

    const float* qp   = qkv + (size_t)b * (3 * DT) + h * D;
    const float* knew = qp + DT;
    const float* vnew = qp + 2 * DT;

    const f4v q4 = ((const f4v*)qp)[l32];

    // ---- K-pass: copy + scores (no loop-carried dependencies) ----
#pragma unroll 8
    for (int it = 0; it < S / 32; ++it) {
        const int r = it * 32 + rg;
        const size_t off = (size_t)r * 32 + l32;
        f4v k4 = __builtin_nontemporal_load(&kin[off]);
        __builtin_nontemporal_store(k4, &kout[off]);
        f4v t = k4 * q4;
        float p = t.x + t.y + t.z + t.w;
        p += __shfl_xor(p, 1);
        p += __shfl_xor(p, 2);
        p += __shfl_xor(p, 4);
        p += __shfl_xor(p, 8);
        p += __shfl_xor(p, 16);
        if (l32 == 0) sc[r] = p * SCALE;
    }
    // new-token score by wave 0
    if (tid < 64) {
        float pd = qp[2 * tid] * knew[2 * tid] + qp[2 * tid + 1] * knew[2 * tid + 1];
        pd += __shfl_xor(pd, 1);
        pd += __shfl_xor(pd, 2);
        pd += __shfl_xor(pd, 4);
        pd += __shfl_xor(pd, 8);
        pd += __shfl_xor(pd, 16);
        pd += __shfl_xor(pd, 32);
        if (tid == 0) sc[S] = pd * SCALE;
    }
    __syncthreads();

    // ---- block softmax over sc[0..2048] ----
    const float s0v = sc[tid];
    const float s1v = sc[tid + 1024];
    const float sxv = (tid == 0) ? sc[S] : -1e30f;
    float m = fmaxf(fmaxf(s0v, s1v), sxv);
#pragma unroll
    for (int off = 1; off < 64; off <<= 1) m = fmaxf(m, __shfl_xor(m, off));
    if (lane == 0) swm[wave] = m;
    __syncthreads();
    float M = swm[0];
#pragma unroll
    for (int g = 1; g < 16; ++g) M = fmaxf(M, swm[g]);
    const float e0 = __expf(s0v - M);
    const float e1 = __expf(s1v - M);
    sc[tid] = e0;
    sc[tid + 1024] = e1;
    float lsum = e0 + e1;
    if (tid == 0) {
        const float e2 = __expf(sxv - M);
        sc[S] = e2;
        lsum += e2;
    }
#pragma unroll
    for (int off = 1; off < 64; off <<= 1) lsum += __shfl_xor(lsum, off);
    if (lane == 0) swl[wave] = lsum;
    __syncthreads();
    float L = swl[0];
#pragma unroll
    for (int g = 1; g < 16; ++g) L += swl[g];
    const float invL = 1.0f / L;

    // ---- V-pass: copy + weighted accumulate (1 carried FMA) ----
    f4v acc = (f4v){0.f, 0.f, 0.f, 0.f};
#pragma unroll 8
    for (int it = 0; it < S / 32; ++it) {
        const int r = it * 32 + rg;
        const size_t off = (size_t)r * 32 + l32;
        f4v v4 = __builtin_nontemporal_load(&vin[off]);
        __builtin_nontemporal_store(v4, &vout[off]);
        acc += v4 * sc[r];
    }

    // ---- combine 32 rowgroups + new token, normalize, write ----
    ((f4v*)sacc)[rg * 32 + l32] = acc;
    __syncthreads();

    if (tid < D) {
        float y = 0.f;
#pragma unroll
        for (int g = 0; g < 32; ++g) y += sacc[g * D + tid];
        y = fmaf(sc[S], vnew[tid], y);
        ys_g[(size_t)bh * D + tid] = y * invL;
    }
}

// ---------------------------------------------------------------------------
// Kernel 3: out-proj + bias + residual + LayerNorm.  One block per b,
// 1024 threads.  GEMV: thread t -> d = t>>3, j-chunk sub = t&7.
// ---------------------------------------------------------------------------
__global__ void __launch_bounds__(1024)
out_proj_kernel(const float* __restrict__ x,
                const float* __restrict__ ys_g,
                const float* __restrict__ Wout,
                const float* __restrict__ bout,
                float* __restrict__ out) {
    const int b = blockIdx.x;
    const int t = threadIdx.x;
    __shared__ float ys[DT];        // 8 KB
    __shared__ float pp[D * 8];     // 4 KB
    __shared__ float tb[D];

    ys[t]        = ys_g[(size_t)b * DT + t];
    ys[t + 1024] = ys_g[(size_t)b * DT + t + 1024];
    __syncthreads();

    {
        const int d = t >> 3;
        const int sub = t & 7;
        const float* w = Wout + (size_t)d * DT + sub * 256;
        const float* y = ys + sub * 256;
        float acc = 0.f;
#pragma unroll
        for (int j = 0; j < 256; j += 4) {
            float4 w4 = *reinterpret_cast<const float4*>(w + j);
            acc = fmaf(w4.x, y[j + 0], acc);
            acc = fmaf(w4.y, y[j + 1], acc);
            acc = fmaf(w4.z, y[j + 2], acc);
            acc = fmaf(w4.w, y[j + 3], acc);
        }
        pp[d * 8 + sub] = acc;
    }
    __syncthreads();

    float val = 0.f;
    if (t < D) {
        float a = 0.f;
#pragma unroll
        for (int g = 0; g < 8; ++g) a += pp[t * 8 + g];
        val = a + bout[t] + x[b * D + t];
        tb[t] = val;
    }
    __syncthreads();
    for (int off = 64; off > 0; off >>= 1) {
        if (t < off) tb[t] += tb[t + off];
        __syncthreads();
    }
    const float mu = tb[0] * (1.0f / D);
    __syncthreads();
    const float diff = val - mu;
    if (t < D) tb[t] = diff * diff;
    __syncthreads();
    for (int off = 64; off > 0; off >>= 1) {
        if (t < off) tb[t] += tb[t + off];
        __syncthreads();
    }
    const float var = tb[0] * (1.0f / D);
    if (t < D) out[(size_t)b * D + t] = diff / sqrtf(var + EPS);
}

// ---------------------------------------------------------------------------
extern "C" void kernel_launch(void* const* d_in, const int* in_sizes, int n_in,
                              void* d_out, int out_size, void* d_ws, size_t ws_size,
                              hipStream_t stream) {
    const float* x      = (const float*)d_in[0];
    const float* past_k = (const float*)d_in[1];
    const float* past_v = (const float*)d_in[2];
    const float* Wqkv   = (const float*)d_in[3];
    const float* bqkv   = (const float*)d_in[4];
    const float* Wout   = (const float*)d_in[5];
    const float* bout   = (const float*)d_in[6];

    float* out   = (float*)d_out;                       // (B,1,D)
    float* out_k = out + (size_t)B * D;                 // (B,H,S1,D)
    float* out_v = out_k + (size_t)B * H * S1 * D;      // (B,H,S1,D)

    float* qkv  = (float*)d_ws;                         // B*3*DT
    float* ys_g = qkv + (size_t)B * 3 * DT;             // B*DT

    qkv_proj_kernel<<<dim3(B, (3 * DT) / 256), 256, 0, stream>>>(
        x, Wqkv, bqkv, qkv, out_k, out_v);
    attn_kernel<<<B * H, 1024, 0, stream>>>(
        past_k, past_v, qkv, out_k, out_v, ys_g);
    out_proj_kernel<<<B, 1024, 0, stream>>>(
        x, ys_g, Wout, bout, out);
}

// Round 7
// 440.910 us; speedup vs baseline: 1.1516x; 1.0099x over previous
//
#include <hip/hip_runtime.h>
#include <math.h>

#define B 32
#define S 2048
#define S1 2049
#define D 128
#define H 16
#define DT 2048   // D*H
#define EPS 1e-5f
#define SCALE 0.08838834764831845f  // 1/sqrt(128)

typedef float f4v __attribute__((ext_vector_type(4)));

// ---------------------------------------------------------------------------
// Kernel 1: fused per-head QKV projection + cache-append + cache-copy +
// full single-(b,h) attention, phase-split.
// Grid: B*H = 512 blocks of 1024 threads = 32 half-waves.
// Prologue: block computes its own q/k_new/v_new (384 length-128 dots; Wqkv
//           head-slices are L2/L3-resident), writes k_new/v_new to cache.
// K-pass:  NT-load K -> regular store to cache -> dot -> score to LDS.
// softmax: block reduction over 2049 scores.
// V-pass:  NT-load V -> regular store to cache -> acc += p * v.
// Stores are REGULAR (not NT): L2 absorbs/coalesces the write stream --
// matching the 6.5 TB/s fill configuration. Loads stay NT (no reuse).
// ---------------------------------------------------------------------------
__global__ void __launch_bounds__(1024)
attn_kernel(const float* __restrict__ x,
            const float* __restrict__ Wqkv,
            const float* __restrict__ bqkv,
            const float* __restrict__ past_k,
            const float* __restrict__ past_v,
            float* __restrict__ out_k,
            float* __restrict__ out_v,
            float* __restrict__ ys_g) {
    const int bh = blockIdx.x;
    const int b = bh >> 4;
    const int h = bh & (H - 1);
    const int tid  = threadIdx.x;
    const int wave = tid >> 6;       // 0..15
    const int lane = tid & 63;
    const int l32  = tid & 31;
    const int rg   = tid >> 5;       // half-wave 0..31

    __shared__ float xs[D];
    __shared__ float qkvs[3 * D];    // q | k_new | v_new for this head
    __shared__ float sc[S1 + 3];     // 2049 scores
    __shared__ float swm[16];
    __shared__ float swl[16];
    __shared__ float sacc[32 * D];   // 16 KB

    const f4v* __restrict__ kin  = (const f4v*)past_k + (size_t)bh * S * 32;
    const f4v* __restrict__ vin  = (const f4v*)past_v + (size_t)bh * S * 32;
    f4v* __restrict__ kout = (f4v*)out_k + (size_t)bh * S1 * 32;
    f4v* __restrict__ vout = (f4v*)out_v + (size_t)bh * S1 * 32;

    // ---- prologue: per-head QKV projection ----
    if (tid < D) xs[tid] = x[b * D + tid];
    __syncthreads();
    if (tid < 3 * D) {
        const int which = tid >> 7;          // 0=q, 1=k_new, 2=v_new
        const int d = tid & 127;
        const int row = which * DT + h * D + d;
        const float* w = Wqkv + (size_t)row * D;
        float acc = bqkv[row];
#pragma unroll
        for (int j = 0; j < D; j += 4) {
            float4 w4 = *reinterpret_cast<const float4*>(w + j);
            acc = fmaf(w4.x, xs[j + 0], acc);
            acc = fmaf(w4.y, xs[j + 1], acc);
            acc = fmaf(w4.z, xs[j + 2], acc);
            acc = fmaf(w4.w, xs[j + 3], acc);
        }
        qkvs[tid] = acc;
        if (which == 1) ((float*)kout)[(size_t)S * D + d] = acc;
        if (which == 2) ((float*)vout)[(size_t)S * D + d] = acc;
    }
    __syncthreads();

    const f4v q4 = ((const f4v*)qkvs)[l32];

    // ---- K-pass: copy + scores (no loop-carried dependencies) ----
#pragma unroll 8
    for (int it = 0; it < S / 32; ++it) {
        const int r = it * 32 + rg;
        const size_t off = (size_t)r * 32 + l32;
        f4v k4 = __builtin_nontemporal_load(&kin[off]);
        kout[off] = k4;
        f4v t = k4 * q4;
        float p = t.x + t.y + t.z + t.w;
        p += __shfl_xor(p, 1);
        p += __shfl_xor(p, 2);
        p += __shfl_xor(p, 4);
        p += __shfl_xor(p, 8);
        p += __shfl_xor(p, 16);
        if (l32 == 0) sc[r] = p * SCALE;
    }
    // new-token score by wave 0 (from LDS q/k_new)
    if (tid < 64) {
        float pd = qkvs[2 * tid] * qkvs[D + 2 * tid]
                 + qkvs[2 * tid + 1] * qkvs[D + 2 * tid + 1];
        pd += __shfl_xor(pd, 1);
        pd += __shfl_xor(pd, 2);
        pd += __shfl_xor(pd, 4);
        pd += __shfl_xor(pd, 8);
        pd += __shfl_xor(pd, 16);
        pd += __shfl_xor(pd, 32);
        if (tid == 0) sc[S] = pd * SCALE;
    }
    __syncthreads();

    // ---- block softmax over sc[0..2048] ----
    const float s0v = sc[tid];
    const float s1v = sc[tid + 1024];
    const float sxv = (tid == 0) ? sc[S] : -1e30f;
    float m = fmaxf(fmaxf(s0v, s1v), sxv);
#pragma unroll
    for (int off = 1; off < 64; off <<= 1) m = fmaxf(m, __shfl_xor(m, off));
    if (lane == 0) swm[wave] = m;
    __syncthreads();
    float M = swm[0];
#pragma unroll
    for (int g = 1; g < 16; ++g) M = fmaxf(M, swm[g]);
    const float e0 = __expf(s0v - M);
    const float e1 = __expf(s1v - M);
    sc[tid] = e0;
    sc[tid + 1024] = e1;
    float lsum = e0 + e1;
    if (tid == 0) {
        const float e2 = __expf(sxv - M);
        sc[S] = e2;
        lsum += e2;
    }
#pragma unroll
    for (int off = 1; off < 64; off <<= 1) lsum += __shfl_xor(lsum, off);
    if (lane == 0) swl[wave] = lsum;
    __syncthreads();
    float L = swl[0];
#pragma unroll
    for (int g = 1; g < 16; ++g) L += swl[g];
    const float invL = 1.0f / L;

    // ---- V-pass: copy + weighted accumulate (1 carried FMA) ----
    f4v acc = (f4v){0.f, 0.f, 0.f, 0.f};
#pragma unroll 8
    for (int it = 0; it < S / 32; ++it) {
        const int r = it * 32 + rg;
        const size_t off = (size_t)r * 32 + l32;
        f4v v4 = __builtin_nontemporal_load(&vin[off]);
        vout[off] = v4;
        acc += v4 * sc[r];
    }

    // ---- combine 32 rowgroups + new token, normalize, write ----
    ((f4v*)sacc)[rg * 32 + l32] = acc;
    __syncthreads();

    if (tid < D) {
        float y = 0.f;
#pragma unroll
        for (int g = 0; g < 32; ++g) y += sacc[g * D + tid];
        y = fmaf(sc[S], qkvs[2 * D + tid], y);
        ys_g[(size_t)bh * D + tid] = y * invL;
    }
}

// ---------------------------------------------------------------------------
// Kernel 2: out-proj + bias + residual + LayerNorm.  One block per b,
// 1024 threads.  GEMV: thread t -> d = t>>3, j-chunk sub = t&7.
// ---------------------------------------------------------------------------
__global__ void __launch_bounds__(1024)
out_proj_kernel(const float* __restrict__ x,
                const float* __restrict__ ys_g,
                const float* __restrict__ Wout,
                const float* __restrict__ bout,
                float* __restrict__ out) {
    const int b = blockIdx.x;
    const int t = threadIdx.x;
    __shared__ float ys[DT];        // 8 KB
    __shared__ float pp[D * 8];     // 4 KB
    __shared__ float tb[D];

    ys[t]        = ys_g[(size_t)b * DT + t];
    ys[t + 1024] = ys_g[(size_t)b * DT + t + 1024];
    __syncthreads();

    {
        const int d = t >> 3;
        const int sub = t & 7;
        const float* w = Wout + (size_t)d * DT + sub * 256;
        const float* y = ys + sub * 256;
        float acc = 0.f;
#pragma unroll
        for (int j = 0; j < 256; j += 4) {
            float4 w4 = *reinterpret_cast<const float4*>(w + j);
            acc = fmaf(w4.x, y[j + 0], acc);
            acc = fmaf(w4.y, y[j + 1], acc);
            acc = fmaf(w4.z, y[j + 2], acc);
            acc = fmaf(w4.w, y[j + 3], acc);
        }
        pp[d * 8 + sub] = acc;
    }
    __syncthreads();

    float val = 0.f;
    if (t < D) {
        float a = 0.f;
#pragma unroll
        for (int g = 0; g < 8; ++g) a += pp[t * 8 + g];
        val = a + bout[t] + x[b * D + t];
        tb[t] = val;
    }
    __syncthreads();
    for (int off = 64; off > 0; off >>= 1) {
        if (t < off) tb[t] += tb[t + off];
        __syncthreads();
    }
    const float mu = tb[0] * (1.0f / D);
    __syncthreads();
    const float diff = val - mu;
    if (t < D) tb[t] = diff * diff;
    __syncthreads();
    for (int off = 64; off > 0; off >>= 1) {
        if (t < off) tb[t] += tb[t + off];
        __syncthreads();
    }
    const float var = tb[0] * (1.0f / D);
    if (t < D) out[(size_t)b * D + t] = diff / sqrtf(var + EPS);
}

// ---------------------------------------------------------------------------
extern "C" void kernel_launch(void* const* d_in, const int* in_sizes, int n_in,
                              void* d_out, int out_size, void* d_ws, size_t ws_size,
                              hipStream_t stream) {
    const float* x      = (const float*)d_in[0];
    const float* past_k = (const float*)d_in[1];
    const float* past_v = (const float*)d_in[2];
    const float* Wqkv   = (const float*)d_in[3];
    const float* bqkv   = (const float*)d_in[4];
    const float* Wout   = (const float*)d_in[5];
    const float* bout   = (const float*)d_in[6];

    float* out   = (float*)d_out;                       // (B,1,D)
    float* out_k = out + (size_t)B * D;                 // (B,H,S1,D)
    float* out_v = out_k + (size_t)B * H * S1 * D;      // (B,H,S1,D)

    float* ys_g = (float*)d_ws;                         // B*DT

    attn_kernel<<<B * H, 1024, 0, stream>>>(
        x, Wqkv, bqkv, past_k, past_v, out_k, out_v, ys_g);
    out_proj_kernel<<<B, 1024, 0, stream>>>(
        x, ys_g, Wout, bout, out);
}